// Round 1
// baseline (289.809 us; speedup 1.0000x reference)
//
#include <hip/hip_runtime.h>
#include <cstddef>
#include <cstdint>

#define H 128
#define EDIM 16
#define NLAYER 3
#define TM 64
#define TN 64
#define TK 16

// Generic tiled GEMM: C[M,N] = A[M,K] @ B + bias(broadcast over rows).
// B is addressed as B[(j>>7)*(K*128) + k*128 + (j&127)] which covers:
//  - row-major [K,128] matrices (node_W, edge_b slice, root_W slice) when N==128
//  - edge_W[l] viewed as [ED,128,128] -> B(k=i, j=d*128+o) when N==ED*128
__global__ __launch_bounds__(256) void gemm_bsliced(
    const float* __restrict__ A, const float* __restrict__ B,
    const float* __restrict__ bias, float* __restrict__ C,
    int M, int K, int N)
{
    __shared__ float As[TK][TM + 4];
    __shared__ float Bs[TK][TN + 4];
    const int bm = blockIdx.y * TM;
    const int bn = blockIdx.x * TN;
    const int tid = threadIdx.x;
    const int tx = tid & 15;
    const int ty = tid >> 4;

    float acc[4][4];
#pragma unroll
    for (int i = 0; i < 4; ++i)
#pragma unroll
        for (int j = 0; j < 4; ++j) acc[i][j] = 0.f;

    const int slice = bn >> 7;            // constant within a 64-wide tile
    const int lo0 = bn & 127;
    const float* Bbase = B + (size_t)slice * ((size_t)K << 7);

    const int ka = tid & 15, ma = tid >> 4;   // A-load mapping (coalesced in k)
    const int nb = tid & 63, kb = tid >> 6;   // B-load mapping (coalesced in n)

    for (int k0 = 0; k0 < K; k0 += TK) {
#pragma unroll
        for (int r = 0; r < 4; ++r)
            As[ka][ma + 16 * r] = A[(size_t)(bm + ma + 16 * r) * K + (k0 + ka)];
#pragma unroll
        for (int r = 0; r < 4; ++r)
            Bs[kb + 4 * r][nb] = Bbase[(size_t)(k0 + kb + 4 * r) * 128 + lo0 + nb];
        __syncthreads();
#pragma unroll
        for (int kk = 0; kk < TK; ++kk) {
            const float4 a4 = *(const float4*)&As[kk][ty * 4];
            const float4 b4 = *(const float4*)&Bs[kk][tx * 4];
            const float a[4] = {a4.x, a4.y, a4.z, a4.w};
            const float b[4] = {b4.x, b4.y, b4.z, b4.w};
#pragma unroll
            for (int i = 0; i < 4; ++i)
#pragma unroll
                for (int j = 0; j < 4; ++j)
                    acc[i][j] = fmaf(a[i], b[j], acc[i][j]);
        }
        __syncthreads();
    }

#pragma unroll
    for (int i = 0; i < 4; ++i) {
        const int row = bm + ty * 4 + i;
        float bj[4] = {0.f, 0.f, 0.f, 0.f};
        if (bias) {
#pragma unroll
            for (int j = 0; j < 4; ++j) bj[j] = bias[(bn + tx * 4 + j) & 127];
        }
        float4 v;
        v.x = acc[i][0] + bj[0];
        v.y = acc[i][1] + bj[1];
        v.z = acc[i][2] + bj[2];
        v.w = acc[i][3] + bj[3];
        *(float4*)&C[(size_t)row * N + bn + tx * 4] = v;
    }
}

__global__ void count_kernel(const int* __restrict__ dst, const int* __restrict__ batch,
                             float* cntN, float* cntG, int E, int N)
{
    int t = blockIdx.x * 256 + threadIdx.x;
    if (t < E) atomicAdd(&cntN[dst[t]], 1.f);
    if (t < N) atomicAdd(&cntG[batch[t]], 1.f);
}

// msg[e,o] = sum_d ea[e,d] * P[src, d*128+o] + Q[src,o]; scatter-add into agg[dst]
__global__ __launch_bounds__(256) void edge_combine(
    const float* __restrict__ P, const float* __restrict__ Q,
    const float* __restrict__ ea, const int* __restrict__ src,
    const int* __restrict__ dst, float* __restrict__ agg, int E)
{
    const int e = blockIdx.x * 2 + (threadIdx.x >> 7);
    const int o = threadIdx.x & 127;
    if (e >= E) return;
    const int s = src[e];
    const int d = dst[e];
    const float* Pe = P + (size_t)s * (EDIM * H);
    float m = Q[s * H + o];
#pragma unroll
    for (int dd = 0; dd < EDIM; ++dd)
        m = fmaf(ea[e * EDIM + dd], Pe[dd * H + o], m);
    atomicAdd(&agg[d * H + o], m);
}

// xnew[v] += agg[v]/max(cnt,1); accumulate per-channel sum & sumsq (32 rows/block)
__global__ __launch_bounds__(256) void stats_kernel(
    float* __restrict__ xnew, const float* __restrict__ agg,
    const float* __restrict__ cnt, float* __restrict__ bnS, float* __restrict__ bnQ, int N)
{
    __shared__ float s1[H], s2[H];
    const int c = threadIdx.x & 127;
    const int half = threadIdx.x >> 7;
    const int row0 = blockIdx.x * 32;
    float s = 0.f, q = 0.f;
    for (int r = half; r < 32; r += 2) {
        const int v = row0 + r;
        const float rc = 1.0f / fmaxf(cnt[v], 1.0f);
        const int idx = v * H + c;
        const float val = xnew[idx] + agg[idx] * rc;
        xnew[idx] = val;
        s += val;
        q += val * val;
    }
    if (half == 1) { s1[c] = s; s2[c] = q; }
    __syncthreads();
    if (half == 0) {
        atomicAdd(&bnS[c], s + s1[c]);
        atomicAdd(&bnQ[c], q + s2[c]);
    }
}

// h += relu((xnew - mu) * rsqrt(var+eps) * gamma + beta)
__global__ __launch_bounds__(256) void bn_apply(
    float* __restrict__ h, const float* __restrict__ xnew,
    const float* __restrict__ bnS, const float* __restrict__ bnQ,
    const float* __restrict__ gamma, const float* __restrict__ beta, int N)
{
    const int idx = blockIdx.x * 256 + threadIdx.x;
    const int c = idx & 127;
    const float invN = 1.0f / (float)N;
    const float mu = bnS[c] * invN;
    const float var = bnQ[c] * invN - mu * mu;
    const float val = (xnew[idx] - mu) * rsqrtf(var + 1e-5f) * gamma[c] + beta[c];
    h[idx] += fmaxf(val, 0.f);
}

__global__ void pool_kernel(const float* __restrict__ h, const int* __restrict__ batch,
                            float* __restrict__ gsum, int N)
{
    const int idx = blockIdx.x * 256 + threadIdx.x;
    const int v = idx >> 7;
    const int c = idx & 127;
    atomicAdd(&gsum[batch[v] * H + c], h[idx]);
}

// out[g] = relu(mean_pool(g) @ W1 + b1) @ W2 + b2
__global__ void classifier_kernel(
    const float* __restrict__ gsum, const float* __restrict__ cntG,
    const float* __restrict__ W1, const float* __restrict__ b1,
    const float* __restrict__ W2, const float* __restrict__ b2,
    float* __restrict__ out)
{
    const int g = blockIdx.x;
    const int j = threadIdx.x;  // 64
    const float rc = 1.0f / fmaxf(cntG[g], 1.0f);
    float acc = b1[j];
#pragma unroll 8
    for (int i = 0; i < H; ++i)
        acc = fmaf(gsum[g * H + i] * rc, W1[i * 64 + j], acc);
    float pv = fmaxf(acc, 0.f) * W2[j];
#pragma unroll
    for (int off = 32; off > 0; off >>= 1)
        pv += __shfl_down(pv, off);
    if (j == 0) out[g] = pv + b2[0];
}

extern "C" void kernel_launch(void* const* d_in, const int* in_sizes, int n_in,
                              void* d_out, int out_size, void* d_ws, size_t ws_size,
                              hipStream_t stream)
{
    const float* x      = (const float*)d_in[0];
    const int*   eidx   = (const int*)  d_in[1];
    const float* eattr  = (const float*)d_in[2];
    const int*   batch  = (const int*)  d_in[3];
    const float* node_W = (const float*)d_in[4];
    const float* node_b = (const float*)d_in[5];
    const float* edge_W = (const float*)d_in[6];
    const float* edge_b = (const float*)d_in[7];
    const float* root_W = (const float*)d_in[8];
    const float* conv_b = (const float*)d_in[9];
    const float* gamma  = (const float*)d_in[10];
    const float* beta   = (const float*)d_in[11];
    const float* W1     = (const float*)d_in[12];
    const float* b1     = (const float*)d_in[13];
    const float* W2     = (const float*)d_in[14];
    const float* b2     = (const float*)d_in[15];
    float* out = (float*)d_out;

    const int N = in_sizes[0] / 32;   // 2048 nodes
    const int E = in_sizes[1] / 2;    // 8192 edges
    const int G = out_size;           // 128 graphs

    float* ws = (float*)d_ws;
    float* h    = ws;                          // N*H
    float* xnew = h    + (size_t)N * H;        // N*H
    float* agg  = xnew + (size_t)N * H;        // N*H
    float* Q    = agg  + (size_t)N * H;        // N*H
    float* cntN = Q    + (size_t)N * H;        // N
    float* cntG = cntN + N;                    // G
    float* bnS  = cntG + G;                    // 3*H
    float* bnQ  = bnS  + NLAYER * H;           // 3*H
    float* gsum = bnQ  + NLAYER * H;           // G*H
    float* P    = gsum + (size_t)G * H;        // N*ED*H

    // zero: counts + BN accumulators + pool sums (contiguous region)
    const size_t zf = (size_t)N + G + 2 * NLAYER * H + (size_t)G * H;
    hipMemsetAsync(cntN, 0, zf * sizeof(float), stream);

    const int* src = eidx;
    const int* dst = eidx + E;

    const int tmax = (E > N ? E : N);
    count_kernel<<<(tmax + 255) / 256, 256, 0, stream>>>(dst, batch, cntN, cntG, E, N);

    // h = x @ node_W + node_b
    gemm_bsliced<<<dim3(H / TN, N / TM), 256, 0, stream>>>(x, node_W, node_b, h, N, 32, H);

    for (int l = 0; l < NLAYER; ++l) {
        hipMemsetAsync(agg, 0, (size_t)N * H * sizeof(float), stream);
        // P[v, d*128+o] = sum_i h[v,i] * edge_W[l][d, i*128+o]
        gemm_bsliced<<<dim3((EDIM * H) / TN, N / TM), 256, 0, stream>>>(
            h, edge_W + (size_t)l * EDIM * H * H, nullptr, P, N, H, EDIM * H);
        // Q[v,o] = sum_i h[v,i] * edge_b[l][i*128+o]
        gemm_bsliced<<<dim3(H / TN, N / TM), 256, 0, stream>>>(
            h, edge_b + (size_t)l * H * H, nullptr, Q, N, H, H);
        edge_combine<<<(E + 1) / 2, 256, 0, stream>>>(P, Q, eattr, src, dst, agg, E);
        // xnew = h @ root_W[l] + conv_bias[l]
        gemm_bsliced<<<dim3(H / TN, N / TM), 256, 0, stream>>>(
            h, root_W + (size_t)l * H * H, conv_b + (size_t)l * H, xnew, N, H, H);
        stats_kernel<<<N / 32, 256, 0, stream>>>(xnew, agg, cntN, bnS + l * H, bnQ + l * H, N);
        bn_apply<<<(N * H) / 256, 256, 0, stream>>>(h, xnew, bnS + l * H, bnQ + l * H,
                                                    gamma + (size_t)l * H, beta + (size_t)l * H, N);
    }

    pool_kernel<<<(N * H) / 256, 256, 0, stream>>>(h, batch, gsum, N);
    classifier_kernel<<<G, 64, 0, stream>>>(gsum, cntG, W1, b1, W2, b2, out);
}

// Round 2
// 208.057 us; speedup vs baseline: 1.3929x; 1.3929x over previous
//
#include <hip/hip_runtime.h>
#include <cstddef>
#include <cstdint>

#define H 128
#define EDIM 16
#define NLAYER 3
#define NSLICE 18            // 16 edge_W slices + edge_b + root_W
#define WCOLS (NSLICE * H)   // 2304
#define TM 64
#define TN 64
#define TK 16

typedef unsigned short ushort_t;
typedef unsigned int uint_t;
typedef __attribute__((ext_vector_type(8))) short bf16x8;
typedef __attribute__((ext_vector_type(4))) float f32x4;

__device__ __forceinline__ ushort_t f2bf(float f) {
    uint_t u = __builtin_bit_cast(uint_t, f);
    u += 0x7fffu + ((u >> 16) & 1u);   // round-to-nearest-even
    return (ushort_t)(u >> 16);
}

// ---------------- fp32 tiled GEMM (node embed only: M=2048,K=32,N=128) -----
__global__ __launch_bounds__(256) void gemm_bsliced(
    const float* __restrict__ A, const float* __restrict__ B,
    const float* __restrict__ bias, float* __restrict__ C,
    ushort_t* __restrict__ Cbf, int M, int K, int N)
{
    __shared__ float As[TK][TM + 4];
    __shared__ float Bs[TK][TN + 4];
    const int bm = blockIdx.y * TM;
    const int bn = blockIdx.x * TN;
    const int tid = threadIdx.x;
    const int tx = tid & 15;
    const int ty = tid >> 4;

    float acc[4][4];
#pragma unroll
    for (int i = 0; i < 4; ++i)
#pragma unroll
        for (int j = 0; j < 4; ++j) acc[i][j] = 0.f;

    const int ka = tid & 15, ma = tid >> 4;
    const int nb = tid & 63, kb = tid >> 6;

    for (int k0 = 0; k0 < K; k0 += TK) {
#pragma unroll
        for (int r = 0; r < 4; ++r)
            As[ka][ma + 16 * r] = A[(size_t)(bm + ma + 16 * r) * K + (k0 + ka)];
#pragma unroll
        for (int r = 0; r < 4; ++r)
            Bs[kb + 4 * r][nb] = B[(size_t)(k0 + kb + 4 * r) * N + bn + nb];
        __syncthreads();
#pragma unroll
        for (int kk = 0; kk < TK; ++kk) {
            const float4 a4 = *(const float4*)&As[kk][ty * 4];
            const float4 b4 = *(const float4*)&Bs[kk][tx * 4];
            const float a[4] = {a4.x, a4.y, a4.z, a4.w};
            const float b[4] = {b4.x, b4.y, b4.z, b4.w};
#pragma unroll
            for (int i = 0; i < 4; ++i)
#pragma unroll
                for (int j = 0; j < 4; ++j)
                    acc[i][j] = fmaf(a[i], b[j], acc[i][j]);
        }
        __syncthreads();
    }

#pragma unroll
    for (int i = 0; i < 4; ++i) {
        const int row = bm + ty * 4 + i;
        float4 v;
        v.x = acc[i][0] + bias[(bn + tx * 4 + 0) & 127];
        v.y = acc[i][1] + bias[(bn + tx * 4 + 1) & 127];
        v.z = acc[i][2] + bias[(bn + tx * 4 + 2) & 127];
        v.w = acc[i][3] + bias[(bn + tx * 4 + 3) & 127];
        *(float4*)&C[(size_t)row * N + bn + tx * 4] = v;
        if (Cbf) {
            ushort_t* o = &Cbf[(size_t)row * N + bn + tx * 4];
            o[0] = f2bf(v.x); o[1] = f2bf(v.y); o[2] = f2bf(v.z); o[3] = f2bf(v.w);
        }
    }
}

// ------------- weights: fp32 [k][o] slices -> bf16 Wt[l][n=2304][k=128] ----
__global__ __launch_bounds__(256) void prep_weights(
    const float* __restrict__ eW, const float* __restrict__ eb,
    const float* __restrict__ rW, ushort_t* __restrict__ Wt)
{
    __shared__ ushort_t tile[128][136];
    const int b = blockIdx.x;            // 54 = 3 layers * 18 slices
    const int l = b / NSLICE, s = b % NSLICE;
    const float* S = (s < 16) ? (eW + ((size_t)l * 16 + s) * (H * H))
                   : (s == 16 ? (eb + (size_t)l * H * H)
                              : (rW + (size_t)l * H * H));
    const int t = threadIdx.x;
    const int k = t >> 1, o0 = (t & 1) * 64;
#pragma unroll
    for (int j = 0; j < 64; j += 4) {
        float4 v = *(const float4*)&S[(size_t)k * H + o0 + j];
        tile[k][o0 + j + 0] = f2bf(v.x);
        tile[k][o0 + j + 1] = f2bf(v.y);
        tile[k][o0 + j + 2] = f2bf(v.z);
        tile[k][o0 + j + 3] = f2bf(v.w);
    }
    __syncthreads();
    const int n = t >> 1, k0 = (t & 1) * 64;
    ushort_t* out = Wt + ((size_t)l * WCOLS + s * H + n) * H + k0;
#pragma unroll 8
    for (int j = 0; j < 64; ++j) out[j] = tile[k0 + j][n];
}

// ------------- bf16 MFMA GEMM: C[2048, 2304] = hbf[2048,128] @ Wt_l^T ------
// Wt is [n][k] (transposed), K=128 entirely in LDS, no k-loop.
__global__ __launch_bounds__(256) void mfma_gemm(
    const ushort_t* __restrict__ hbf, const ushort_t* __restrict__ Wt,
    float* __restrict__ C)
{
    __shared__ ushort_t As[64][136];
    __shared__ ushort_t Bs[64][136];
    const int tid = threadIdx.x;
    const int v0 = blockIdx.y * 64;
    const int n0 = blockIdx.x * 64;

    {   // cooperative loads: thread t -> row t>>2, 32 ushorts at col (t&3)*32
        const int row = tid >> 2, col0 = (tid & 3) * 32;
        const ushort_t* ga = hbf + (size_t)(v0 + row) * H + col0;
        const ushort_t* gb = Wt + (size_t)(n0 + row) * H + col0;
#pragma unroll
        for (int j = 0; j < 32; j += 8) {
            *(uint4*)&As[row][col0 + j] = *(const uint4*)(ga + j);
            *(uint4*)&Bs[row][col0 + j] = *(const uint4*)(gb + j);
        }
    }
    __syncthreads();

    const int wave = tid >> 6, lane = tid & 63;
    const int l15 = lane & 15, kg = lane >> 4;
    const int mrow = wave * 16 + l15;

    f32x4 acc0 = {0.f, 0.f, 0.f, 0.f};
    f32x4 acc1 = {0.f, 0.f, 0.f, 0.f};
    f32x4 acc2 = {0.f, 0.f, 0.f, 0.f};
    f32x4 acc3 = {0.f, 0.f, 0.f, 0.f};

#pragma unroll
    for (int s = 0; s < 4; ++s) {
        const int k = s * 32 + kg * 8;
        bf16x8 a = *(const bf16x8*)&As[mrow][k];
        bf16x8 b0 = *(const bf16x8*)&Bs[0 * 16 + l15][k];
        bf16x8 b1 = *(const bf16x8*)&Bs[1 * 16 + l15][k];
        bf16x8 b2 = *(const bf16x8*)&Bs[2 * 16 + l15][k];
        bf16x8 b3 = *(const bf16x8*)&Bs[3 * 16 + l15][k];
        acc0 = __builtin_amdgcn_mfma_f32_16x16x32_bf16(a, b0, acc0, 0, 0, 0);
        acc1 = __builtin_amdgcn_mfma_f32_16x16x32_bf16(a, b1, acc1, 0, 0, 0);
        acc2 = __builtin_amdgcn_mfma_f32_16x16x32_bf16(a, b2, acc2, 0, 0, 0);
        acc3 = __builtin_amdgcn_mfma_f32_16x16x32_bf16(a, b3, acc3, 0, 0, 0);
    }

    // D: col = lane&15, row = (lane>>4)*4 + reg
    const size_t base = (size_t)(v0 + wave * 16 + kg * 4) * WCOLS + n0 + l15;
#pragma unroll
    for (int r = 0; r < 4; ++r) {
        C[base + (size_t)r * WCOLS + 0]  = acc0[r];
        C[base + (size_t)r * WCOLS + 16] = acc1[r];
        C[base + (size_t)r * WCOLS + 32] = acc2[r];
        C[base + (size_t)r * WCOLS + 48] = acc3[r];
    }
}

// ---------------------------------------------------------------------------
__global__ void count_kernel(const int* __restrict__ dst, const int* __restrict__ batch,
                             float* cntN, float* cntG, int E, int N)
{
    int t = blockIdx.x * 256 + threadIdx.x;
    if (t < E) atomicAdd(&cntN[dst[t]], 1.f);
    if (t < N) atomicAdd(&cntG[batch[t]], 1.f);
}

// msg[e,o] = sum_d ea[e,d]*P[src, d*128+o] + Q[src,o]; scatter-add into agg[dst]
__global__ __launch_bounds__(256) void edge_combine(
    const float* __restrict__ Pbuf, const float* __restrict__ ea,
    const int* __restrict__ src, const int* __restrict__ dst,
    float* __restrict__ agg, int E)
{
    const int e = blockIdx.x * 2 + (threadIdx.x >> 7);
    const int o = threadIdx.x & 127;
    if (e >= E) return;
    const int s = src[e], d = dst[e];
    const float* Pe = Pbuf + (size_t)s * WCOLS;
    float m = Pe[16 * H + o];            // Q slice
#pragma unroll
    for (int dd = 0; dd < EDIM; ++dd)
        m = fmaf(ea[e * EDIM + dd], Pe[dd * H + o], m);
    atomicAdd(&agg[d * H + o], m);
}

// xnew = root_slice + conv_bias + agg/cnt ; accumulate BN sum/sumsq
__global__ __launch_bounds__(256) void stats_kernel(
    const float* __restrict__ Pbuf, const float* __restrict__ agg,
    const float* __restrict__ cnt, const float* __restrict__ conv_b,
    float* __restrict__ xnew, float* __restrict__ bnS, float* __restrict__ bnQ)
{
    __shared__ float s1[H], s2[H];
    const int c = threadIdx.x & 127;
    const int half = threadIdx.x >> 7;
    const int row0 = blockIdx.x * 32;
    const float cb = conv_b[c];
    float s = 0.f, q = 0.f;
    for (int r = half; r < 32; r += 2) {
        const int v = row0 + r;
        const float rc = 1.0f / fmaxf(cnt[v], 1.0f);
        const float val = Pbuf[(size_t)v * WCOLS + 17 * H + c] + cb
                        + agg[v * H + c] * rc;
        xnew[v * H + c] = val;
        s += val;
        q += val * val;
    }
    if (half == 1) { s1[c] = s; s2[c] = q; }
    __syncthreads();
    if (half == 0) {
        atomicAdd(&bnS[c], s + s1[c]);
        atomicAdd(&bnQ[c], q + s2[c]);
    }
}

// h += relu(bn(xnew)); also write h_bf; on last layer scatter into gsum
__global__ __launch_bounds__(256) void bn_apply(
    float* __restrict__ h, ushort_t* __restrict__ hbf,
    const float* __restrict__ xnew,
    const float* __restrict__ bnS, const float* __restrict__ bnQ,
    const float* __restrict__ gamma, const float* __restrict__ beta,
    const int* __restrict__ batch, float* __restrict__ gsum, int N, int last)
{
    const int idx = blockIdx.x * 256 + threadIdx.x;
    const int c = idx & 127;
    const int v = idx >> 7;
    const float invN = 1.0f / (float)N;
    const float mu = bnS[c] * invN;
    const float var = bnQ[c] * invN - mu * mu;
    const float val = (xnew[idx] - mu) * rsqrtf(var + 1e-5f) * gamma[c] + beta[c];
    const float hn = h[idx] + fmaxf(val, 0.f);
    h[idx] = hn;
    hbf[idx] = f2bf(hn);
    if (last) atomicAdd(&gsum[batch[v] * H + c], hn);
}

__global__ void classifier_kernel(
    const float* __restrict__ gsum, const float* __restrict__ cntG,
    const float* __restrict__ W1, const float* __restrict__ b1,
    const float* __restrict__ W2, const float* __restrict__ b2,
    float* __restrict__ out)
{
    const int g = blockIdx.x;
    const int j = threadIdx.x;  // 64
    const float rc = 1.0f / fmaxf(cntG[g], 1.0f);
    float acc = b1[j];
#pragma unroll 8
    for (int i = 0; i < H; ++i)
        acc = fmaf(gsum[g * H + i] * rc, W1[i * 64 + j], acc);
    float pv = fmaxf(acc, 0.f) * W2[j];
#pragma unroll
    for (int off = 32; off > 0; off >>= 1)
        pv += __shfl_down(pv, off);
    if (j == 0) out[g] = pv + b2[0];
}

extern "C" void kernel_launch(void* const* d_in, const int* in_sizes, int n_in,
                              void* d_out, int out_size, void* d_ws, size_t ws_size,
                              hipStream_t stream)
{
    const float* x      = (const float*)d_in[0];
    const int*   eidx   = (const int*)  d_in[1];
    const float* eattr  = (const float*)d_in[2];
    const int*   batch  = (const int*)  d_in[3];
    const float* node_W = (const float*)d_in[4];
    const float* node_b = (const float*)d_in[5];
    const float* edge_W = (const float*)d_in[6];
    const float* edge_b = (const float*)d_in[7];
    const float* root_W = (const float*)d_in[8];
    const float* conv_b = (const float*)d_in[9];
    const float* gamma  = (const float*)d_in[10];
    const float* beta   = (const float*)d_in[11];
    const float* W1     = (const float*)d_in[12];
    const float* b1     = (const float*)d_in[13];
    const float* W2     = (const float*)d_in[14];
    const float* b2     = (const float*)d_in[15];
    float* out = (float*)d_out;

    const int N = in_sizes[0] / 32;   // 2048
    const int E = in_sizes[1] / 2;    // 8192
    const int G = out_size;           // 128

    float* ws = (float*)d_ws;
    // --- zero region (one memset) ---
    float* agg  = ws;                                    // 3*N*H
    float* cntN = agg  + (size_t)3 * N * H;              // N
    float* cntG = cntN + N;                              // G
    float* bnS  = cntG + G;                              // 3*H
    float* bnQ  = bnS  + NLAYER * H;                     // 3*H
    float* gsum = bnQ  + NLAYER * H;                     // G*H
    // --- rest ---
    float* h    = gsum + (size_t)G * H;                  // N*H
    float* xnew = h    + (size_t)N * H;                  // N*H
    ushort_t* hbf = (ushort_t*)(xnew + (size_t)N * H);   // N*H bf16
    ushort_t* Wt  = hbf + (size_t)N * H;                 // 3*2304*128 bf16
    float* Pbuf = (float*)(Wt + (size_t)NLAYER * WCOLS * H);  // N*2304

    const size_t zf = (size_t)3 * N * H + N + G + 2 * NLAYER * H + (size_t)G * H;
    hipMemsetAsync(agg, 0, zf * sizeof(float), stream);

    const int* src = eidx;
    const int* dst = eidx + E;

    const int tmax = (E > N ? E : N);
    count_kernel<<<(tmax + 255) / 256, 256, 0, stream>>>(dst, batch, cntN, cntG, E, N);

    prep_weights<<<NLAYER * NSLICE, 256, 0, stream>>>(edge_W, edge_b, root_W, Wt);

    // h = x @ node_W + node_b (fp32, K=32), also emit hbf
    gemm_bsliced<<<dim3(H / TN, N / TM), 256, 0, stream>>>(
        x, node_W, node_b, h, hbf, N, 32, H);

    for (int l = 0; l < NLAYER; ++l) {
        float* agg_l = agg + (size_t)l * N * H;
        mfma_gemm<<<dim3(WCOLS / 64, N / 64), 256, 0, stream>>>(
            hbf, Wt + (size_t)l * WCOLS * H, Pbuf);
        edge_combine<<<E / 2, 256, 0, stream>>>(Pbuf, eattr, src, dst, agg_l, E);
        stats_kernel<<<N / 32, 256, 0, stream>>>(
            Pbuf, agg_l, cntN, conv_b + (size_t)l * H, xnew, bnS + l * H, bnQ + l * H);
        bn_apply<<<(N * H) / 256, 256, 0, stream>>>(
            h, hbf, xnew, bnS + l * H, bnQ + l * H,
            gamma + (size_t)l * H, beta + (size_t)l * H,
            batch, gsum, N, l == NLAYER - 1);
    }

    classifier_kernel<<<G, 64, 0, stream>>>(gsum, cntG, W1, b1, W2, b2, out);
}

// Round 3
// 205.732 us; speedup vs baseline: 1.4087x; 1.0113x over previous
//
#include <hip/hip_runtime.h>
#include <cstddef>
#include <cstdint>

#define H 128
#define EDIM 16
#define NLAYER 3
#define NSLICE 18            // 16 edge_W slices + edge_b + root_W
#define WCOLS (NSLICE * H)   // 2304
#define PCOLS (EDIM * H)     // 2048 bf16 cols of P
#define TM 64
#define TN 64
#define TK 16

typedef unsigned short ushort_t;
typedef unsigned int uint_t;
typedef __attribute__((ext_vector_type(8))) short bf16x8;
typedef __attribute__((ext_vector_type(4))) float f32x4;

__device__ __forceinline__ ushort_t f2bf(float f) {
    uint_t u = __builtin_bit_cast(uint_t, f);
    u += 0x7fffu + ((u >> 16) & 1u);   // RNE
    return (ushort_t)(u >> 16);
}
__device__ __forceinline__ float bf_lo(uint_t u) {
    return __builtin_bit_cast(float, u << 16);
}
__device__ __forceinline__ float bf_hi(uint_t u) {
    return __builtin_bit_cast(float, u & 0xffff0000u);
}

// ---- setup: edge/graph histograms (blocks 0..31) + weight prep (32..85) ----
__global__ __launch_bounds__(256) void setup_kernel(
    const int* __restrict__ dst, const int* __restrict__ batch,
    int* __restrict__ hist, float* __restrict__ cntG, int E, int N,
    const float* __restrict__ eW, const float* __restrict__ eb,
    const float* __restrict__ rW, ushort_t* __restrict__ Wt)
{
    if (blockIdx.x < 32) {
        int t = blockIdx.x * 256 + threadIdx.x;
        if (t < E) atomicAdd(&hist[dst[t]], 1);
        if (t < N) atomicAdd(&cntG[batch[t]], 1.f);
        return;
    }
    // weight prep: fp32 [k][o] slice -> bf16 Wt[l][n][k]
    __shared__ ushort_t tile[128][136];
    const int b = blockIdx.x - 32;       // 0..53
    const int l = b / NSLICE, s = b % NSLICE;
    const float* S = (s < 16) ? (eW + ((size_t)l * 16 + s) * (H * H))
                   : (s == 16 ? (eb + (size_t)l * H * H)
                              : (rW + (size_t)l * H * H));
    const int t = threadIdx.x;
    const int k = t >> 1, o0 = (t & 1) * 64;
#pragma unroll
    for (int j = 0; j < 64; j += 4) {
        float4 v = *(const float4*)&S[(size_t)k * H + o0 + j];
        tile[k][o0 + j + 0] = f2bf(v.x);
        tile[k][o0 + j + 1] = f2bf(v.y);
        tile[k][o0 + j + 2] = f2bf(v.z);
        tile[k][o0 + j + 3] = f2bf(v.w);
    }
    __syncthreads();
    const int n = t >> 1, k0 = (t & 1) * 64;
    ushort_t* outp = Wt + ((size_t)l * WCOLS + s * H + n) * H + k0;
#pragma unroll 8
    for (int j = 0; j < 64; ++j) outp[j] = tile[k0 + j][n];
}

// ---- exclusive scan of hist[0..N) -> offs[0..N], one block, N=2048 --------
__global__ __launch_bounds__(256) void scan_kernel(
    const int* __restrict__ hist, int* __restrict__ offs, int N)
{
    __shared__ int part[256];
    const int t = threadIdx.x;
    const int base = t * 8;
    int v[8], loc[8], s = 0;
#pragma unroll
    for (int j = 0; j < 8; ++j) v[j] = hist[base + j];
#pragma unroll
    for (int j = 0; j < 8; ++j) { loc[j] = s; s += v[j]; }
    part[t] = s;
    __syncthreads();
    for (int off = 1; off < 256; off <<= 1) {
        int x = (t >= off) ? part[t - off] : 0;
        __syncthreads();
        part[t] += x;
        __syncthreads();
    }
    const int boff = (t == 0) ? 0 : part[t - 1];
#pragma unroll
    for (int j = 0; j < 8; ++j) offs[base + j] = boff + loc[j];
    if (t == 255) offs[N] = boff + s;
}

__global__ void scatter_kernel(const int* __restrict__ dst,
                               const int* __restrict__ offs,
                               int* __restrict__ fill, int* __restrict__ eord, int E)
{
    const int e = blockIdx.x * 256 + threadIdx.x;
    if (e >= E) return;
    const int d = dst[e];
    const int pos = offs[d] + atomicAdd(&fill[d], 1);
    eord[pos] = e;
}

// ---------------- fp32 tiled GEMM (node embed: M=2048,K=32,N=128) ----------
__global__ __launch_bounds__(256) void gemm_embed(
    const float* __restrict__ A, const float* __restrict__ B,
    const float* __restrict__ bias, float* __restrict__ C,
    ushort_t* __restrict__ Cbf, int M, int K, int N)
{
    __shared__ float As[TK][TM + 4];
    __shared__ float Bs[TK][TN + 4];
    const int bm = blockIdx.y * TM;
    const int bn = blockIdx.x * TN;
    const int tid = threadIdx.x;
    const int tx = tid & 15;
    const int ty = tid >> 4;

    float acc[4][4];
#pragma unroll
    for (int i = 0; i < 4; ++i)
#pragma unroll
        for (int j = 0; j < 4; ++j) acc[i][j] = 0.f;

    const int ka = tid & 15, ma = tid >> 4;
    const int nb = tid & 63, kb = tid >> 6;

    for (int k0 = 0; k0 < K; k0 += TK) {
#pragma unroll
        for (int r = 0; r < 4; ++r)
            As[ka][ma + 16 * r] = A[(size_t)(bm + ma + 16 * r) * K + (k0 + ka)];
#pragma unroll
        for (int r = 0; r < 4; ++r)
            Bs[kb + 4 * r][nb] = B[(size_t)(k0 + kb + 4 * r) * N + bn + nb];
        __syncthreads();
#pragma unroll
        for (int kk = 0; kk < TK; ++kk) {
            const float4 a4 = *(const float4*)&As[kk][ty * 4];
            const float4 b4 = *(const float4*)&Bs[kk][tx * 4];
            const float a[4] = {a4.x, a4.y, a4.z, a4.w};
            const float b[4] = {b4.x, b4.y, b4.z, b4.w};
#pragma unroll
            for (int i = 0; i < 4; ++i)
#pragma unroll
                for (int j = 0; j < 4; ++j)
                    acc[i][j] = fmaf(a[i], b[j], acc[i][j]);
        }
        __syncthreads();
    }

#pragma unroll
    for (int i = 0; i < 4; ++i) {
        const int row = bm + ty * 4 + i;
        float4 v;
        v.x = acc[i][0] + bias[(bn + tx * 4 + 0) & 127];
        v.y = acc[i][1] + bias[(bn + tx * 4 + 1) & 127];
        v.z = acc[i][2] + bias[(bn + tx * 4 + 2) & 127];
        v.w = acc[i][3] + bias[(bn + tx * 4 + 3) & 127];
        *(float4*)&C[(size_t)row * N + bn + tx * 4] = v;
        ushort_t* o = &Cbf[(size_t)row * N + bn + tx * 4];
        o[0] = f2bf(v.x); o[1] = f2bf(v.y); o[2] = f2bf(v.z); o[3] = f2bf(v.w);
    }
}

// ---- bf16 MFMA GEMM: [2048,128]@Wt^T -> Pb (bf16, slices 0..15) + QR fp32 -
__global__ __launch_bounds__(256) void mfma_gemm(
    const ushort_t* __restrict__ hbf, const ushort_t* __restrict__ Wt,
    ushort_t* __restrict__ Pb, float* __restrict__ QR)
{
    __shared__ ushort_t As[64][136];
    __shared__ ushort_t Bs[64][136];
    const int tid = threadIdx.x;
    const int v0 = blockIdx.y * 64;
    const int n0 = blockIdx.x * 64;

    {
        const int row = tid >> 2, col0 = (tid & 3) * 32;
        const ushort_t* ga = hbf + (size_t)(v0 + row) * H + col0;
        const ushort_t* gb = Wt + (size_t)(n0 + row) * H + col0;
#pragma unroll
        for (int j = 0; j < 32; j += 8) {
            *(uint4*)&As[row][col0 + j] = *(const uint4*)(ga + j);
            *(uint4*)&Bs[row][col0 + j] = *(const uint4*)(gb + j);
        }
    }
    __syncthreads();

    const int wave = tid >> 6, lane = tid & 63;
    const int l15 = lane & 15, kg = lane >> 4;
    const int mrow = wave * 16 + l15;

    f32x4 acc0 = {0.f, 0.f, 0.f, 0.f};
    f32x4 acc1 = {0.f, 0.f, 0.f, 0.f};
    f32x4 acc2 = {0.f, 0.f, 0.f, 0.f};
    f32x4 acc3 = {0.f, 0.f, 0.f, 0.f};

#pragma unroll
    for (int s = 0; s < 4; ++s) {
        const int k = s * 32 + kg * 8;
        bf16x8 a = *(const bf16x8*)&As[mrow][k];
        bf16x8 b0 = *(const bf16x8*)&Bs[0 * 16 + l15][k];
        bf16x8 b1 = *(const bf16x8*)&Bs[1 * 16 + l15][k];
        bf16x8 b2 = *(const bf16x8*)&Bs[2 * 16 + l15][k];
        bf16x8 b3 = *(const bf16x8*)&Bs[3 * 16 + l15][k];
        acc0 = __builtin_amdgcn_mfma_f32_16x16x32_bf16(a, b0, acc0, 0, 0, 0);
        acc1 = __builtin_amdgcn_mfma_f32_16x16x32_bf16(a, b1, acc1, 0, 0, 0);
        acc2 = __builtin_amdgcn_mfma_f32_16x16x32_bf16(a, b2, acc2, 0, 0, 0);
        acc3 = __builtin_amdgcn_mfma_f32_16x16x32_bf16(a, b3, acc3, 0, 0, 0);
    }

    // D: col = lane&15, row = (lane>>4)*4 + reg
    const int slice = n0 >> 7;
    const int lo = n0 & 127;
    const int row0 = v0 + wave * 16 + kg * 4;
    if (slice < 16) {
        ushort_t* op = Pb + (size_t)row0 * PCOLS + slice * H + lo + l15;
#pragma unroll
        for (int r = 0; r < 4; ++r) {
            op[(size_t)r * PCOLS + 0]  = f2bf(acc0[r]);
            op[(size_t)r * PCOLS + 16] = f2bf(acc1[r]);
            op[(size_t)r * PCOLS + 32] = f2bf(acc2[r]);
            op[(size_t)r * PCOLS + 48] = f2bf(acc3[r]);
        }
    } else {
        float* op = QR + (size_t)row0 * 256 + (slice - 16) * H + lo + l15;
#pragma unroll
        for (int r = 0; r < 4; ++r) {
            op[(size_t)r * 256 + 0]  = acc0[r];
            op[(size_t)r * 256 + 16] = acc1[r];
            op[(size_t)r * 256 + 32] = acc2[r];
            op[(size_t)r * 256 + 48] = acc3[r];
        }
    }
}

// ---- fused per-node edge aggregation (CSR, no atomics) + mean + BN stats --
// block = 256 threads = 4 sub-blocks x 64 threads; sub-block sb handles node
// v = blockIdx.x*4 + sb; thread handles channel pair (2*o2, 2*o2+1).
__global__ __launch_bounds__(256) void edge_stats(
    const ushort_t* __restrict__ Pb, const float* __restrict__ QR,
    const float* __restrict__ ea, const int* __restrict__ srcArr,
    const int* __restrict__ offs, const int* __restrict__ hist,
    const int* __restrict__ eord, const float* __restrict__ conv_b,
    float* __restrict__ xnew, float* __restrict__ bnS, float* __restrict__ bnQ)
{
    __shared__ float sS[4][H];
    __shared__ float sQ[4][H];
    const int tid = threadIdx.x;
    const int sb = tid >> 6;
    const int o2 = tid & 63;          // channel pair
    const int v = blockIdx.x * 4 + sb;

    const int st = offs[v];
    const int deg = hist[v];
    float m0 = 0.f, m1 = 0.f;
    for (int k = 0; k < deg; ++k) {
        const int e = eord[st + k];
        const int s = srcArr[e];
        const float* eap = ea + (size_t)e * EDIM;
        const float4 w0 = *(const float4*)(eap + 0);
        const float4 w1 = *(const float4*)(eap + 4);
        const float4 w2 = *(const float4*)(eap + 8);
        const float4 w3 = *(const float4*)(eap + 12);
        const float w[16] = {w0.x, w0.y, w0.z, w0.w, w1.x, w1.y, w1.z, w1.w,
                             w2.x, w2.y, w2.z, w2.w, w3.x, w3.y, w3.z, w3.w};
        const uint_t* prow = (const uint_t*)(Pb + (size_t)s * PCOLS) + o2;
        const float2 q2 = *(const float2*)(QR + (size_t)s * 256 + 2 * o2);
        m0 += q2.x;
        m1 += q2.y;
#pragma unroll
        for (int d = 0; d < EDIM; ++d) {
            const uint_t u = prow[(size_t)d * 64];
            m0 = fmaf(w[d], bf_lo(u), m0);
            m1 = fmaf(w[d], bf_hi(u), m1);
        }
    }
    const float rc = 1.0f / (float)(deg > 0 ? deg : 1);
    const float2 rt = *(const float2*)(QR + (size_t)v * 256 + H + 2 * o2);
    const float2 cb = *(const float2*)(conv_b + 2 * o2);
    const float val0 = m0 * rc + rt.x + cb.x;
    const float val1 = m1 * rc + rt.y + cb.y;
    *(float2*)(xnew + (size_t)v * H + 2 * o2) = make_float2(val0, val1);
    sS[sb][2 * o2] = val0; sS[sb][2 * o2 + 1] = val1;
    sQ[sb][2 * o2] = val0 * val0; sQ[sb][2 * o2 + 1] = val1 * val1;
    __syncthreads();
    if (tid < H) {
        const float s4 = sS[0][tid] + sS[1][tid] + sS[2][tid] + sS[3][tid];
        const float q4 = sQ[0][tid] + sQ[1][tid] + sQ[2][tid] + sQ[3][tid];
        atomicAdd(&bnS[tid], s4);
        atomicAdd(&bnQ[tid], q4);
    }
}

// ---- h += relu(bn(xnew)); emit h_bf; last layer scatters into gsum --------
__global__ __launch_bounds__(256) void bn_apply(
    float* __restrict__ h, ushort_t* __restrict__ hbf,
    const float* __restrict__ xnew,
    const float* __restrict__ bnS, const float* __restrict__ bnQ,
    const float* __restrict__ gamma, const float* __restrict__ beta,
    const int* __restrict__ batch, float* __restrict__ gsum, int N, int last)
{
    const int idx = blockIdx.x * 256 + threadIdx.x;
    const int c = idx & 127;
    const int v = idx >> 7;
    const float invN = 1.0f / (float)N;
    const float mu = bnS[c] * invN;
    const float var = bnQ[c] * invN - mu * mu;
    const float val = (xnew[idx] - mu) * rsqrtf(var + 1e-5f) * gamma[c] + beta[c];
    const float hn = h[idx] + fmaxf(val, 0.f);
    h[idx] = hn;
    hbf[idx] = f2bf(hn);
    if (last) atomicAdd(&gsum[batch[v] * H + c], hn);
}

__global__ void classifier_kernel(
    const float* __restrict__ gsum, const float* __restrict__ cntG,
    const float* __restrict__ W1, const float* __restrict__ b1,
    const float* __restrict__ W2, const float* __restrict__ b2,
    float* __restrict__ out)
{
    const int g = blockIdx.x;
    const int j = threadIdx.x;  // 64
    const float rc = 1.0f / fmaxf(cntG[g], 1.0f);
    float acc = b1[j];
#pragma unroll 8
    for (int i = 0; i < H; ++i)
        acc = fmaf(gsum[g * H + i] * rc, W1[i * 64 + j], acc);
    float pv = fmaxf(acc, 0.f) * W2[j];
#pragma unroll
    for (int off = 32; off > 0; off >>= 1)
        pv += __shfl_down(pv, off);
    if (j == 0) out[g] = pv + b2[0];
}

extern "C" void kernel_launch(void* const* d_in, const int* in_sizes, int n_in,
                              void* d_out, int out_size, void* d_ws, size_t ws_size,
                              hipStream_t stream)
{
    const float* x      = (const float*)d_in[0];
    const int*   eidx   = (const int*)  d_in[1];
    const float* eattr  = (const float*)d_in[2];
    const int*   batch  = (const int*)  d_in[3];
    const float* node_W = (const float*)d_in[4];
    const float* node_b = (const float*)d_in[5];
    const float* edge_W = (const float*)d_in[6];
    const float* edge_b = (const float*)d_in[7];
    const float* root_W = (const float*)d_in[8];
    const float* conv_b = (const float*)d_in[9];
    const float* gamma  = (const float*)d_in[10];
    const float* beta   = (const float*)d_in[11];
    const float* W1     = (const float*)d_in[12];
    const float* b1     = (const float*)d_in[13];
    const float* W2     = (const float*)d_in[14];
    const float* b2     = (const float*)d_in[15];
    float* out = (float*)d_out;

    const int N = in_sizes[0] / 32;   // 2048
    const int E = in_sizes[1] / 2;    // 8192
    const int G = out_size;           // 128

    // ---- workspace layout (all 16B aligned) ----
    int* hist   = (int*)d_ws;                         // N
    int* fill   = hist + N;                           // N
    float* cntG = (float*)(fill + N);                 // G
    float* bnS  = cntG + G;                           // 3*H
    float* bnQ  = bnS + NLAYER * H;                   // 3*H
    float* gsum = bnQ + NLAYER * H;                   // G*H
    // --- end of zero region ---
    int* offs   = (int*)(gsum + (size_t)G * H);       // N+1, padded to N+16
    int* eord   = offs + (N + 16);                    // E
    float* h    = (float*)(eord + E);                 // N*H
    float* xnew = h + (size_t)N * H;                  // N*H
    ushort_t* hbf = (ushort_t*)(xnew + (size_t)N * H);        // N*H
    ushort_t* Wt  = hbf + (size_t)N * H;                      // 3*WCOLS*H
    ushort_t* Pb  = Wt + (size_t)NLAYER * WCOLS * H;          // N*PCOLS
    float* QR   = (float*)(Pb + (size_t)N * PCOLS);           // N*256

    const size_t zbytes = (size_t)(2 * N) * 4
                        + ((size_t)G + 2 * NLAYER * H + (size_t)G * H) * 4;
    hipMemsetAsync(hist, 0, zbytes, stream);

    const int* src = eidx;
    const int* dst = eidx + E;

    setup_kernel<<<32 + NLAYER * NSLICE, 256, 0, stream>>>(
        dst, batch, hist, cntG, E, N, edge_W, edge_b, root_W, Wt);
    scan_kernel<<<1, 256, 0, stream>>>(hist, offs, N);
    scatter_kernel<<<E / 256, 256, 0, stream>>>(dst, offs, fill, eord, E);

    gemm_embed<<<dim3(H / TN, N / TM), 256, 0, stream>>>(
        x, node_W, node_b, h, hbf, N, 32, H);

    for (int l = 0; l < NLAYER; ++l) {
        mfma_gemm<<<dim3(WCOLS / 64, N / 64), 256, 0, stream>>>(
            hbf, Wt + (size_t)l * WCOLS * H, Pb, QR);
        edge_stats<<<N / 4, 256, 0, stream>>>(
            Pb, QR, eattr, src, offs, hist, eord,
            conv_b + (size_t)l * H, xnew, bnS + l * H, bnQ + l * H);
        bn_apply<<<(N * H) / 256, 256, 0, stream>>>(
            h, hbf, xnew, bnS + l * H, bnQ + l * H,
            gamma + (size_t)l * H, beta + (size_t)l * H,
            batch, gsum, N, l == NLAYER - 1);
    }

    classifier_kernel<<<G, 64, 0, stream>>>(gsum, cntG, W1, b1, W2, b2, out);
}